// Round 3
// baseline (18691.985 us; speedup 1.0000x reference)
//
#include <hip/hip_runtime.h>
#include <hip/hip_bf16.h>
#include <math.h>

// Problem constants (fixed by the reference)
#define T_STEPS 4096
#define N_IN    8192
#define N_OUT   2048

// ---------------------------------------------------------------------------
// Kernel 1: u_proj = x @ Win   (f32 vector GEMM, 128x128 tile, BK=16)
//   Writes into d_out; the recurrence consumes/overwrites it in place.
// ---------------------------------------------------------------------------
#define GM_BK 16

__global__ __launch_bounds__(256) void gemm_xwin(const float* __restrict__ X,
                                                 const float* __restrict__ Win,
                                                 float* __restrict__ U) {
    const int K = N_IN, N = N_OUT;
    __shared__ float As[GM_BK][128 + 4];
    __shared__ float Bs[GM_BK][128 + 4];

    const int tid = threadIdx.x;
    const int bm = blockIdx.x;
    const int bn = blockIdx.y;
    const int tx = tid & 15;
    const int ty = tid >> 4;

    float acc[8][8];
#pragma unroll
    for (int i = 0; i < 8; i++)
#pragma unroll
        for (int j = 0; j < 8; j++) acc[i][j] = 0.f;

    const float* Xb = X + (size_t)(bm * 128) * K;
    const float* Wb = Win + bn * 128;

    for (int kt = 0; kt < K; kt += GM_BK) {
#pragma unroll
        for (int q = 0; q < 2; q++) {
            const int r  = (tid >> 2) + q * 64;
            const int c4 = (tid & 3) * 4;
            const float4 a4 = *reinterpret_cast<const float4*>(&Xb[(size_t)r * K + kt + c4]);
            As[c4 + 0][r] = a4.x;
            As[c4 + 1][r] = a4.y;
            As[c4 + 2][r] = a4.z;
            As[c4 + 3][r] = a4.w;
        }
#pragma unroll
        for (int q = 0; q < 2; q++) {
            const int r  = (tid >> 5) + q * 8;
            const int c4 = (tid & 31) * 4;
            *reinterpret_cast<float4*>(&Bs[r][c4]) =
                *reinterpret_cast<const float4*>(&Wb[(size_t)(kt + r) * N + c4]);
        }
        __syncthreads();

#pragma unroll
        for (int k = 0; k < GM_BK; k++) {
            float a[8], b[8];
#pragma unroll
            for (int i = 0; i < 4; i++) {
                a[i]     = As[k][ty * 4 + i];
                a[4 + i] = As[k][64 + ty * 4 + i];
            }
#pragma unroll
            for (int j = 0; j < 4; j++) {
                b[j]     = Bs[k][tx * 4 + j];
                b[4 + j] = Bs[k][64 + tx * 4 + j];
            }
#pragma unroll
            for (int i = 0; i < 8; i++)
#pragma unroll
                for (int j = 0; j < 8; j++)
                    acc[i][j] = fmaf(a[i], b[j], acc[i][j]);
        }
        __syncthreads();
    }

#pragma unroll
    for (int i = 0; i < 8; i++) {
        const int mr = bm * 128 + ((i < 4) ? (ty * 4 + i) : (64 + ty * 4 + (i - 4)));
        float* Crow = U + (size_t)mr * N + bn * 128;
        float4 v0 = make_float4(acc[i][0], acc[i][1], acc[i][2], acc[i][3]);
        float4 v1 = make_float4(acc[i][4], acc[i][5], acc[i][6], acc[i][7]);
        *reinterpret_cast<float4*>(&Crow[tx * 4])      = v0;
        *reinterpret_cast<float4*>(&Crow[64 + tx * 4]) = v1;
    }
}

// ---------------------------------------------------------------------------
// Kernel 2: sequential ESN recurrence, tagged-slot exchange v3.
//   - bitmask-round polling: all pending slot loads re-issued concurrently
//     (retries cost ONE LLC round trip, not one per straggler slot)
//   - vsh double-buffered in LDS -> single __syncthreads per step
//   - MAC unrolled x2; slot store issued before the UO store
//   Reuse invariant: a producer only observes tag t on ALL slots after every
//   block passed its step t-1 barrier, i.e. all parity-(t-1) reads are done,
//   so overwriting parity-(t+1)==(t-1) slots is safe.
// ---------------------------------------------------------------------------
#define RB   256   // blocks (== CU count, co-resident by construction)
#define CPB  8     // columns per block
#define GRP  32    // lanes per column
#define CAP  352   // nnz capacity per column (mean 204.8, sigma 13.6)

__global__ __launch_bounds__(256) void esn_recur(const float* __restrict__ W,
                                                 float* __restrict__ UO,
                                                 unsigned long long* vslots) {
    __shared__ unsigned long long ent[CPB][CAP];  // {idx (hi32), w bits (lo32)}
    __shared__ int   cnts[CPB];
    __shared__ float vsh[2][N_OUT];               // double-buffered state

    const int tid = threadIdx.x;
    const int b   = blockIdx.x;
    const int c   = tid >> 5;              // column group 0..7
    const int l   = tid & 31;              // lane within group
    const int j   = b * CPB + c;           // global output column

    // ---------- build sparse column (one-time) ----------
    int cnt = 0;
    for (int k = 0; k < N_OUT / GRP; k++) {
        const float w = W[(size_t)(l + GRP * k) * N_OUT + j];
        cnt += (w != 0.0f) ? 1 : 0;
    }
    int inc = cnt;
#pragma unroll
    for (int d = 1; d < GRP; d <<= 1) {
        int n = __shfl_up(inc, d, 64);
        if (l >= d) inc += n;
    }
    int pos = inc - cnt;
    if (l == GRP - 1) cnts[c] = inc;
    for (int k = 0; k < N_OUT / GRP; k++) {
        const int i = l + GRP * k;
        const float w = W[(size_t)i * N_OUT + j];
        if (w != 0.0f) {
            if (pos < CAP)
                ent[c][pos] = ((unsigned long long)(unsigned)i << 32) | __float_as_uint(w);
            pos++;
        }
    }
    __syncthreads();
    const int ccnt = min(cnts[c], CAP);

    // ---------- sequential scan over T ----------
#pragma unroll 1
    for (int t = 0; t < T_STEPS; t++) {
        // prefetch this step's input projection (independent of v_t)
        float u = 0.f;
        if (l == 0) u = UO[(size_t)t * N_OUT + j];

        // ---- poll tagged slots for v_t: bitmask rounds, all pending in flight
        unsigned long long* vin = vslots + (size_t)(t & 1) * N_OUT;
        float* dst = vsh[t & 1];
        unsigned long long uq[8];
#pragma unroll
        for (int q = 0; q < 8; q++)
            uq[q] = __hip_atomic_load(&vin[tid + q * 256], __ATOMIC_RELAXED,
                                      __HIP_MEMORY_SCOPE_AGENT);
        unsigned pend = 0xFFu;
#pragma unroll 1
        while (true) {
            unsigned np = 0;
#pragma unroll
            for (int q = 0; q < 8; q++) {
                if (pend & (1u << q)) {
                    if ((unsigned)(uq[q] >> 32) == (unsigned)t)
                        dst[tid + q * 256] = __uint_as_float((unsigned)uq[q]);
                    else
                        np |= (1u << q);
                }
            }
            pend = np;
            if (!pend) break;
#pragma unroll
            for (int q = 0; q < 8; q++)
                if (pend & (1u << q))
                    uq[q] = __hip_atomic_load(&vin[tid + q * 256], __ATOMIC_RELAXED,
                                              __HIP_MEMORY_SCOPE_AGENT);
        }
        __syncthreads();   // vsh[t&1] complete (single barrier per step)

        // ---- sparse MAC: y[j] = sum_i W[i][j] * v_t[i], unrolled x2
        const float* vcur = vsh[t & 1];
        float y = 0.f;
        int p = l;
#pragma unroll 1
        for (; p + GRP < ccnt; p += 2 * GRP) {
            const unsigned long long e0 = ent[c][p];
            const unsigned long long e1 = ent[c][p + GRP];
            y = fmaf(__uint_as_float((unsigned)e0), vcur[e0 >> 32], y);
            y = fmaf(__uint_as_float((unsigned)e1), vcur[e1 >> 32], y);
        }
        if (p < ccnt) {
            const unsigned long long e = ent[c][p];
            y = fmaf(__uint_as_float((unsigned)e), vcur[e >> 32], y);
        }
#pragma unroll
        for (int d = 16; d >= 1; d >>= 1) y += __shfl_xor(y, d, 64);

        if (l == 0) {
            const float vnew = 0.5f * vcur[j] + 0.5f * tanhf(y + u);
            // slot store FIRST (inter-block critical path), then the output
            const unsigned long long slot =
                ((unsigned long long)(unsigned)(t + 1) << 32) | __float_as_uint(vnew);
            __hip_atomic_store(&vslots[(size_t)((t + 1) & 1) * N_OUT + j], slot,
                               __ATOMIC_RELAXED, __HIP_MEMORY_SCOPE_AGENT);
            UO[(size_t)t * N_OUT + j] = vnew;
        }
        // no trailing barrier: next step writes vsh[(t+1)&1]; threads can only
        // reach that write after this step's barrier, and parity-(t+1) reads
        // finished before it (collective barrier argument above).
    }
}

// ---------------------------------------------------------------------------
extern "C" void kernel_launch(void* const* d_in, const int* in_sizes, int n_in,
                              void* d_out, int out_size, void* d_ws, size_t ws_size,
                              hipStream_t stream) {
    const float* x   = (const float*)d_in[0];   // [4096, 8192]
    const float* W   = (const float*)d_in[1];   // [2048, 2048]
    const float* Win = (const float*)d_in[2];   // [8192, 2048]
    float* out = (float*)d_out;                 // [4096, 2048]

    unsigned long long* vslots = (unsigned long long*)d_ws;  // 2 x N_OUT x 8B

    // zero tags+values: slot[0] becomes {tag=0, v=0} == the ESN zero state
    hipMemsetAsync(d_ws, 0, 2 * N_OUT * sizeof(unsigned long long), stream);

    dim3 ggrid(T_STEPS / 128, N_OUT / 128);
    gemm_xwin<<<ggrid, 256, 0, stream>>>(x, Win, out);

    esn_recur<<<RB, 256, 0, stream>>>(W, out, vslots);
}

// Round 4
// 17160.474 us; speedup vs baseline: 1.0892x; 1.0892x over previous
//
#include <hip/hip_runtime.h>
#include <hip/hip_bf16.h>
#include <math.h>

// Problem constants (fixed by the reference)
#define T_STEPS 4096
#define N_IN    8192
#define N_OUT   2048

// ---------------------------------------------------------------------------
// Kernel 1: u_proj = x @ Win   (f32 vector GEMM, 128x128 tile, BK=16)
//   Writes into d_out; the recurrence consumes/overwrites it in place.
// ---------------------------------------------------------------------------
#define GM_BK 16

__global__ __launch_bounds__(256) void gemm_xwin(const float* __restrict__ X,
                                                 const float* __restrict__ Win,
                                                 float* __restrict__ U) {
    const int K = N_IN, N = N_OUT;
    __shared__ float As[GM_BK][128 + 4];
    __shared__ float Bs[GM_BK][128 + 4];

    const int tid = threadIdx.x;
    const int bm = blockIdx.x;
    const int bn = blockIdx.y;
    const int tx = tid & 15;
    const int ty = tid >> 4;

    float acc[8][8];
#pragma unroll
    for (int i = 0; i < 8; i++)
#pragma unroll
        for (int j = 0; j < 8; j++) acc[i][j] = 0.f;

    const float* Xb = X + (size_t)(bm * 128) * K;
    const float* Wb = Win + bn * 128;

    for (int kt = 0; kt < K; kt += GM_BK) {
#pragma unroll
        for (int q = 0; q < 2; q++) {
            const int r  = (tid >> 2) + q * 64;
            const int c4 = (tid & 3) * 4;
            const float4 a4 = *reinterpret_cast<const float4*>(&Xb[(size_t)r * K + kt + c4]);
            As[c4 + 0][r] = a4.x;
            As[c4 + 1][r] = a4.y;
            As[c4 + 2][r] = a4.z;
            As[c4 + 3][r] = a4.w;
        }
#pragma unroll
        for (int q = 0; q < 2; q++) {
            const int r  = (tid >> 5) + q * 8;
            const int c4 = (tid & 31) * 4;
            *reinterpret_cast<float4*>(&Bs[r][c4]) =
                *reinterpret_cast<const float4*>(&Wb[(size_t)(kt + r) * N + c4]);
        }
        __syncthreads();

#pragma unroll
        for (int k = 0; k < GM_BK; k++) {
            float a[8], b[8];
#pragma unroll
            for (int i = 0; i < 4; i++) {
                a[i]     = As[k][ty * 4 + i];
                a[4 + i] = As[k][64 + ty * 4 + i];
            }
#pragma unroll
            for (int j = 0; j < 4; j++) {
                b[j]     = Bs[k][tx * 4 + j];
                b[4 + j] = Bs[k][64 + tx * 4 + j];
            }
#pragma unroll
            for (int i = 0; i < 8; i++)
#pragma unroll
                for (int j = 0; j < 8; j++)
                    acc[i][j] = fmaf(a[i], b[j], acc[i][j]);
        }
        __syncthreads();
    }

#pragma unroll
    for (int i = 0; i < 8; i++) {
        const int mr = bm * 128 + ((i < 4) ? (ty * 4 + i) : (64 + ty * 4 + (i - 4)));
        float* Crow = U + (size_t)mr * N + bn * 128;
        float4 v0 = make_float4(acc[i][0], acc[i][1], acc[i][2], acc[i][3]);
        float4 v1 = make_float4(acc[i][4], acc[i][5], acc[i][6], acc[i][7]);
        *reinterpret_cast<float4*>(&Crow[tx * 4])      = v0;
        *reinterpret_cast<float4*>(&Crow[64 + tx * 4]) = v1;
    }
}

// ---------------------------------------------------------------------------
// Kernel 2: sequential ESN recurrence, tagged-slot exchange v4.
//   KEY CHANGE vs r3: 64 blocks x 32 columns (was 256 x 8) -> 4x fewer poll
//   loads in flight per step (the r2->r3 data showed poll traffic, not
//   straggler serialization, is the cost). Plus s_sleep backoff on retry
//   rounds, pending-only reloads, double-buffered vsh (1 barrier/step).
//   Reuse invariant unchanged: overwriting parity-(t+1)==(t-1) slots is safe
//   because producing v_t requires having read all of v_{t-1}.
// ---------------------------------------------------------------------------
#define RB   64    // blocks (co-resident trivially)
#define CPB  32    // columns per block
#define GRP  8     // lanes per column
#define CAP  288   // nnz capacity per column (mean 204.8, sigma 13.6 -> +6.1s)

__global__ __launch_bounds__(256) void esn_recur(const float* __restrict__ W,
                                                 float* __restrict__ UO,
                                                 unsigned long long* vslots) {
    __shared__ unsigned long long ent[CPB][CAP];  // {idx (hi32), w bits (lo32)}
    __shared__ int   cnts[CPB];
    __shared__ float vsh[2][N_OUT];               // double-buffered state

    const int tid = threadIdx.x;
    const int b   = blockIdx.x;
    const int c   = tid >> 3;              // column group 0..31
    const int l   = tid & 7;               // lane within group
    const int j   = b * CPB + c;           // global output column

    // ---------- build sparse column (one-time) ----------
    int cnt = 0;
    for (int k = 0; k < N_OUT / GRP; k++) {
        const float w = W[(size_t)(l + GRP * k) * N_OUT + j];
        cnt += (w != 0.0f) ? 1 : 0;
    }
    int inc = cnt;
#pragma unroll
    for (int d = 1; d < GRP; d <<= 1) {
        int n = __shfl_up(inc, d, 64);
        if (l >= d) inc += n;
    }
    int pos = inc - cnt;
    if (l == GRP - 1) cnts[c] = inc;
    for (int k = 0; k < N_OUT / GRP; k++) {
        const int i = l + GRP * k;
        const float w = W[(size_t)i * N_OUT + j];
        if (w != 0.0f) {
            if (pos < CAP)
                ent[c][pos] = ((unsigned long long)(unsigned)i << 32) | __float_as_uint(w);
            pos++;
        }
    }
    __syncthreads();
    const int ccnt = min(cnts[c], CAP);

    // ---------- sequential scan over T ----------
#pragma unroll 1
    for (int t = 0; t < T_STEPS; t++) {
        // prefetch this step's input projection (independent of v_t; hides HBM)
        float u = 0.f;
        if (l == 0) u = UO[(size_t)t * N_OUT + j];

        // ---- poll tagged slots for v_t (8 slots/thread, pending-only retries,
        //      s_sleep backoff between rounds to keep the LLC path clear)
        unsigned long long* vin = vslots + (size_t)(t & 1) * N_OUT;
        float* dst = vsh[t & 1];
        unsigned long long uq[8];
#pragma unroll
        for (int q = 0; q < 8; q++)
            uq[q] = __hip_atomic_load(&vin[tid + q * 256], __ATOMIC_RELAXED,
                                      __HIP_MEMORY_SCOPE_AGENT);
        unsigned pend = 0xFFu;
#pragma unroll 1
        while (true) {
            unsigned np = 0;
#pragma unroll
            for (int q = 0; q < 8; q++) {
                if (pend & (1u << q)) {
                    if ((unsigned)(uq[q] >> 32) == (unsigned)t)
                        dst[tid + q * 256] = __uint_as_float((unsigned)uq[q]);
                    else
                        np |= (1u << q);
                }
            }
            pend = np;
            if (!pend) break;
            __builtin_amdgcn_s_sleep(1);   // ~64 cyc backoff: cheap vs round-trip
#pragma unroll
            for (int q = 0; q < 8; q++)
                if (pend & (1u << q))
                    uq[q] = __hip_atomic_load(&vin[tid + q * 256], __ATOMIC_RELAXED,
                                              __HIP_MEMORY_SCOPE_AGENT);
        }
        __syncthreads();   // vsh[t&1] complete (single barrier per step)

        // ---- sparse MAC: y[j] = sum_i W[i][j] * v_t[i], unrolled x2
        const float* vcur = vsh[t & 1];
        float y = 0.f;
        int p = l;
#pragma unroll 1
        for (; p + GRP < ccnt; p += 2 * GRP) {
            const unsigned long long e0 = ent[c][p];
            const unsigned long long e1 = ent[c][p + GRP];
            y = fmaf(__uint_as_float((unsigned)e0), vcur[e0 >> 32], y);
            y = fmaf(__uint_as_float((unsigned)e1), vcur[e1 >> 32], y);
        }
        if (p < ccnt) {
            const unsigned long long e = ent[c][p];
            y = fmaf(__uint_as_float((unsigned)e), vcur[e >> 32], y);
        }
#pragma unroll
        for (int d = GRP / 2; d >= 1; d >>= 1) y += __shfl_xor(y, d, 64);

        if (l == 0) {
            const float vnew = 0.5f * vcur[j] + 0.5f * tanhf(y + u);
            // slot store FIRST (inter-block critical path), then the output
            const unsigned long long slot =
                ((unsigned long long)(unsigned)(t + 1) << 32) | __float_as_uint(vnew);
            __hip_atomic_store(&vslots[(size_t)((t + 1) & 1) * N_OUT + j], slot,
                               __ATOMIC_RELAXED, __HIP_MEMORY_SCOPE_AGENT);
            UO[(size_t)t * N_OUT + j] = vnew;
        }
        // no trailing barrier: next step touches only vsh[(t+1)&1] (see invariant)
    }
}

// ---------------------------------------------------------------------------
extern "C" void kernel_launch(void* const* d_in, const int* in_sizes, int n_in,
                              void* d_out, int out_size, void* d_ws, size_t ws_size,
                              hipStream_t stream) {
    const float* x   = (const float*)d_in[0];   // [4096, 8192]
    const float* W   = (const float*)d_in[1];   // [2048, 2048]
    const float* Win = (const float*)d_in[2];   // [8192, 2048]
    float* out = (float*)d_out;                 // [4096, 2048]

    unsigned long long* vslots = (unsigned long long*)d_ws;  // 2 x N_OUT x 8B

    // zero tags+values: slot[0] becomes {tag=0, v=0} == the ESN zero state
    hipMemsetAsync(d_ws, 0, 2 * N_OUT * sizeof(unsigned long long), stream);

    dim3 ggrid(T_STEPS / 128, N_OUT / 128);
    gemm_xwin<<<ggrid, 256, 0, stream>>>(x, Win, out);

    esn_recur<<<RB, 256, 0, stream>>>(W, out, vslots);
}

// Round 5
// 13366.614 us; speedup vs baseline: 1.3984x; 1.2838x over previous
//
#include <hip/hip_runtime.h>
#include <hip/hip_bf16.h>
#include <math.h>

// Problem constants (fixed by the reference)
#define T_STEPS 4096
#define N_IN    8192
#define N_OUT   2048

// ---------------------------------------------------------------------------
// Kernel 1: u_proj = x @ Win   (f32 vector GEMM, 128x128 tile, BK=16)
//   Writes into d_out; the recurrence consumes/overwrites it in place.
// ---------------------------------------------------------------------------
#define GM_BK 16

__global__ __launch_bounds__(256) void gemm_xwin(const float* __restrict__ X,
                                                 const float* __restrict__ Win,
                                                 float* __restrict__ U) {
    const int K = N_IN, N = N_OUT;
    __shared__ float As[GM_BK][128 + 4];
    __shared__ float Bs[GM_BK][128 + 4];

    const int tid = threadIdx.x;
    const int bm = blockIdx.x;
    const int bn = blockIdx.y;
    const int tx = tid & 15;
    const int ty = tid >> 4;

    float acc[8][8];
#pragma unroll
    for (int i = 0; i < 8; i++)
#pragma unroll
        for (int j = 0; j < 8; j++) acc[i][j] = 0.f;

    const float* Xb = X + (size_t)(bm * 128) * K;
    const float* Wb = Win + bn * 128;

    for (int kt = 0; kt < K; kt += GM_BK) {
#pragma unroll
        for (int q = 0; q < 2; q++) {
            const int r  = (tid >> 2) + q * 64;
            const int c4 = (tid & 3) * 4;
            const float4 a4 = *reinterpret_cast<const float4*>(&Xb[(size_t)r * K + kt + c4]);
            As[c4 + 0][r] = a4.x;
            As[c4 + 1][r] = a4.y;
            As[c4 + 2][r] = a4.z;
            As[c4 + 3][r] = a4.w;
        }
#pragma unroll
        for (int q = 0; q < 2; q++) {
            const int r  = (tid >> 5) + q * 8;
            const int c4 = (tid & 31) * 4;
            *reinterpret_cast<float4*>(&Bs[r][c4]) =
                *reinterpret_cast<const float4*>(&Wb[(size_t)(kt + r) * N + c4]);
        }
        __syncthreads();

#pragma unroll
        for (int k = 0; k < GM_BK; k++) {
            float a[8], b[8];
#pragma unroll
            for (int i = 0; i < 4; i++) {
                a[i]     = As[k][ty * 4 + i];
                a[4 + i] = As[k][64 + ty * 4 + i];
            }
#pragma unroll
            for (int j = 0; j < 4; j++) {
                b[j]     = Bs[k][tx * 4 + j];
                b[4 + j] = Bs[k][64 + tx * 4 + j];
            }
#pragma unroll
            for (int i = 0; i < 8; i++)
#pragma unroll
                for (int j = 0; j < 8; j++)
                    acc[i][j] = fmaf(a[i], b[j], acc[i][j]);
        }
        __syncthreads();
    }

#pragma unroll
    for (int i = 0; i < 8; i++) {
        const int mr = bm * 128 + ((i < 4) ? (ty * 4 + i) : (64 + ty * 4 + (i - 4)));
        float* Crow = U + (size_t)mr * N + bn * 128;
        float4 v0 = make_float4(acc[i][0], acc[i][1], acc[i][2], acc[i][3]);
        float4 v1 = make_float4(acc[i][4], acc[i][5], acc[i][6], acc[i][7]);
        *reinterpret_cast<float4*>(&Crow[tx * 4])      = v0;
        *reinterpret_cast<float4*>(&Crow[64 + tx * 4]) = v1;
    }
}

// ---------------------------------------------------------------------------
// Kernel 2: sequential ESN recurrence, tagged-slot exchange v5.
//   Changes vs r4 (which showed per-step time is SERIAL-LATENCY bound, not
//   traffic bound):
//   - W entries live in REGISTERS (occupancy is 1 block/CU anyway): fixed
//     36-slot padded per-lane entry list -> fully unrolled MAC, zero per-step
//     ent/cnts LDS reads, 4-way accumulator split.
//   - fast branch-free tanh via __expf + v_rcp (libm tanhf was ~100cy on the
//     serial path).
//   - no s_sleep backoff (added detect quantization, no benefit).
//   Reuse invariant unchanged: overwriting parity-(t+1)==(t-1) slots is safe
//   because producing v_t requires having read all of v_{t-1}.
// ---------------------------------------------------------------------------
#define RB   64    // blocks (1 per CU, trivially co-resident)
#define CPB  32    // columns per block
#define GRP  8     // lanes per column
#define CAP  288   // nnz capacity per column (mean 204.8, sigma 13.6 -> +6.1s)
#define KMAX (CAP / GRP)   // 36 register entries per lane

__device__ __forceinline__ float fast_tanh(float x) {
    const float ax = fabsf(x);
    const float e  = __expf(2.0f * ax);              // v_exp path; inf for big ax
    const float r  = __builtin_amdgcn_rcpf(e + 1.0f); // ~1ulp; rcp(inf)=0 -> tanh=1
    const float t  = 1.0f - 2.0f * r;
    return copysignf(t, x);
}

__global__ __launch_bounds__(256, 1) void esn_recur(const float* __restrict__ W,
                                                    float* __restrict__ UO,
                                                    unsigned long long* vslots) {
    __shared__ unsigned long long ent[CPB][CAP];  // setup scratch only
    __shared__ int   cnts[CPB];
    __shared__ float vsh[2][N_OUT];               // double-buffered state

    const int tid = threadIdx.x;
    const int b   = blockIdx.x;
    const int c   = tid >> 3;              // column group 0..31
    const int l   = tid & 7;               // lane within group
    const int j   = b * CPB + c;           // global output column

    // ---------- build sparse column into LDS scratch (one-time) ----------
    int cnt = 0;
    for (int k = 0; k < N_OUT / GRP; k++) {
        const float w = W[(size_t)(l + GRP * k) * N_OUT + j];
        cnt += (w != 0.0f) ? 1 : 0;
    }
    int inc = cnt;
#pragma unroll
    for (int d = 1; d < GRP; d <<= 1) {
        int n = __shfl_up(inc, d, 64);
        if (l >= d) inc += n;
    }
    int pos = inc - cnt;
    if (l == GRP - 1) cnts[c] = inc;
    for (int k = 0; k < N_OUT / GRP; k++) {
        const int i = l + GRP * k;
        const float w = W[(size_t)i * N_OUT + j];
        if (w != 0.0f) {
            if (pos < CAP)
                ent[c][pos] = ((unsigned long long)(unsigned)i << 32) | __float_as_uint(w);
            pos++;
        }
    }
    __syncthreads();
    const int ccnt = min(cnts[c], CAP);

    // ---------- move this lane's entries to REGISTERS, padded to KMAX ----------
    float wreg[KMAX];
    int   ireg[KMAX];   // element index into vsh row (0 if padded; w=0 nullifies)
#pragma unroll
    for (int k = 0; k < KMAX; k++) {
        const int p = l + k * GRP;
        if (p < ccnt) {
            const unsigned long long e = ent[c][p];
            wreg[k] = __uint_as_float((unsigned)e);
            ireg[k] = (int)(e >> 32);
        } else {
            wreg[k] = 0.f;
            ireg[k] = 0;
        }
    }

    // ---------- sequential scan over T ----------
#pragma unroll 1
    for (int t = 0; t < T_STEPS; t++) {
        // prefetch this step's input projection (independent of v_t)
        float u = 0.f;
        if (l == 0) u = UO[(size_t)t * N_OUT + j];

        // ---- poll tagged slots for v_t (8 slots/thread, pending-only retries)
        unsigned long long* vin = vslots + (size_t)(t & 1) * N_OUT;
        float* dst = vsh[t & 1];
        unsigned long long uq[8];
#pragma unroll
        for (int q = 0; q < 8; q++)
            uq[q] = __hip_atomic_load(&vin[tid + q * 256], __ATOMIC_RELAXED,
                                      __HIP_MEMORY_SCOPE_AGENT);
        unsigned pend = 0xFFu;
#pragma unroll 1
        while (true) {
            unsigned np = 0;
#pragma unroll
            for (int q = 0; q < 8; q++) {
                if (pend & (1u << q)) {
                    if ((unsigned)(uq[q] >> 32) == (unsigned)t)
                        dst[tid + q * 256] = __uint_as_float((unsigned)uq[q]);
                    else
                        np |= (1u << q);
                }
            }
            pend = np;
            if (!pend) break;
#pragma unroll
            for (int q = 0; q < 8; q++)
                if (pend & (1u << q))
                    uq[q] = __hip_atomic_load(&vin[tid + q * 256], __ATOMIC_RELAXED,
                                              __HIP_MEMORY_SCOPE_AGENT);
        }
        __syncthreads();   // vsh[t&1] complete (single barrier per step)

        // ---- MAC from registers: 36 independent LDS gathers, 4 accumulators
        const float* vcur = vsh[t & 1];
        float y0 = 0.f, y1 = 0.f, y2 = 0.f, y3 = 0.f;
#pragma unroll
        for (int k = 0; k < KMAX; k += 4) {
            y0 = fmaf(wreg[k + 0], vcur[ireg[k + 0]], y0);
            y1 = fmaf(wreg[k + 1], vcur[ireg[k + 1]], y1);
            y2 = fmaf(wreg[k + 2], vcur[ireg[k + 2]], y2);
            y3 = fmaf(wreg[k + 3], vcur[ireg[k + 3]], y3);
        }
        float y = (y0 + y1) + (y2 + y3);
#pragma unroll
        for (int d = GRP / 2; d >= 1; d >>= 1) y += __shfl_xor(y, d, 64);

        if (l == 0) {
            const float vnew = 0.5f * vcur[j] + 0.5f * fast_tanh(y + u);
            // slot store FIRST (inter-block critical path), then the output
            const unsigned long long slot =
                ((unsigned long long)(unsigned)(t + 1) << 32) | __float_as_uint(vnew);
            __hip_atomic_store(&vslots[(size_t)((t + 1) & 1) * N_OUT + j], slot,
                               __ATOMIC_RELAXED, __HIP_MEMORY_SCOPE_AGENT);
            UO[(size_t)t * N_OUT + j] = vnew;
        }
        // no trailing barrier: next step touches only vsh[(t+1)&1] (see invariant)
    }
}

// ---------------------------------------------------------------------------
extern "C" void kernel_launch(void* const* d_in, const int* in_sizes, int n_in,
                              void* d_out, int out_size, void* d_ws, size_t ws_size,
                              hipStream_t stream) {
    const float* x   = (const float*)d_in[0];   // [4096, 8192]
    const float* W   = (const float*)d_in[1];   // [2048, 2048]
    const float* Win = (const float*)d_in[2];   // [8192, 2048]
    float* out = (float*)d_out;                 // [4096, 2048]

    unsigned long long* vslots = (unsigned long long*)d_ws;  // 2 x N_OUT x 8B

    // zero tags+values: slot[0] becomes {tag=0, v=0} == the ESN zero state
    hipMemsetAsync(d_ws, 0, 2 * N_OUT * sizeof(unsigned long long), stream);

    dim3 ggrid(T_STEPS / 128, N_OUT / 128);
    gemm_xwin<<<ggrid, 256, 0, stream>>>(x, Win, out);

    esn_recur<<<RB, 256, 0, stream>>>(W, out, vslots);
}